// Round 1
// baseline (827.792 us; speedup 1.0000x reference)
//
#include <hip/hip_runtime.h>

#define NPG 100    // nodes per graph
#define EPG 1600   // edges per graph
#define H 64
#define NINP 3
#define H2 32
#define NOUT 10

// One block per graph. 256 threads = 4 waves.
// wave wg owns nodes [wg*25, wg*25+25), lane j owns feature j.
// LDS budget: ~63.6 KB -> 2 blocks/CU.
__launch_bounds__(256, 2)
__global__ void cheb_fused(const float* __restrict__ x,
                           const int*   __restrict__ ei,
                           const float* __restrict__ lambda_max,
                           const float* __restrict__ W1, const float* __restrict__ b1,
                           const float* __restrict__ W2, const float* __restrict__ b2,
                           const float* __restrict__ W3, const float* __restrict__ b3,
                           const float* __restrict__ bng, const float* __restrict__ bnb,
                           const float* __restrict__ bnm, const float* __restrict__ bnv,
                           const float* __restrict__ fc1w, const float* __restrict__ fc1b,
                           const float* __restrict__ fc2w, const float* __restrict__ fc2b,
                           float* __restrict__ out, int E_total)
{
    __shared__ float hb[2][NPG][H];          // 51200 B : Tx ping-pong (width 64)
    __shared__ float ts[2][NPG][NINP];       //  2400 B : Tx ping-pong (width 3, layer 1)
    __shared__ float coefE[EPG];             //  6400 B : CSR edge coefficients
    __shared__ unsigned char colv[EPG];      //  1600 B : CSR col (local id < 100)
    __shared__ int rowstart[NPG + 1];        //   404 B
    __shared__ int sc[128];                  //   512 B : histogram / scan / cursors
    __shared__ float dis[NPG];               //   400 B : deg^-1/2
    __shared__ float pool[H];                //   256 B
    __shared__ float gvn[H];                 //   256 B
    __shared__ float zf[H2];                 //   128 B
    __shared__ float logits[NOUT];           //    40 B
    __shared__ float lse;                    // total ~63.6 KB

    const int tid   = threadIdx.x;
    const int g     = blockIdx.x;
    const int ebase = g * EPG;
    const int nbase = g * NPG;
    const int wg    = tid >> 6;   // wave id 0..3
    const int j     = tid & 63;   // feature lane

    const float lam   = lambda_max[g];
    const float two_l = 2.0f / lam;
    const float cl    = two_l - 1.0f;   // coef_loop (uniform within graph)

    // ---------- build CSR: histogram ----------
    if (tid < 128) sc[tid] = 0;
    __syncthreads();
    for (int e = tid; e < EPG; e += 256) {
        int r = ei[ebase + e] - nbase;       // row = src
        atomicAdd(&sc[r], 1);
    }
    __syncthreads();
    // inclusive Hillis-Steele scan over sc[0..127]
    for (int d = 1; d < 128; d <<= 1) {
        int v = 0;
        if (tid < 128) {
            v = sc[tid];
            if (tid >= d) v += sc[tid - d];
        }
        __syncthreads();
        if (tid < 128) sc[tid] = v;
        __syncthreads();
    }
    if (tid <= NPG) rowstart[tid] = (tid == 0) ? 0 : sc[tid - 1];
    __syncthreads();
    if (tid < NPG) {
        int d = rowstart[tid + 1] - rowstart[tid];
        dis[tid] = (d > 0) ? (1.0f / sqrtf((float)d)) : 0.0f;
    }
    if (tid < NPG) sc[tid] = rowstart[tid];   // cursors
    __syncthreads();
    // ---------- place edges + load x ----------
    for (int e = tid; e < EPG; e += 256) {
        int r = ei[ebase + e] - nbase;
        int c = ei[E_total + ebase + e] - nbase;   // col = dst
        int pos = atomicAdd(&sc[r], 1);
        colv[pos]  = (unsigned char)c;
        coefE[pos] = -two_l * dis[r] * dis[c];
    }
    for (int t = tid; t < NPG * NINP; t += 256) {
        ts[0][t / NINP][t % NINP] = x[nbase * NINP + t];
    }
    __syncthreads();

    float o[25];   // out accumulator: o[i] = out[wg*25+i][j]

    // ---------- layer 1 (feature width 3) ----------
    auto accum3 = [&](const float (*T)[NINP], int k) {
        float w0 = W1[(k * NINP + 0) * H + j];
        float w1 = W1[(k * NINP + 1) * H + j];
        float w2 = W1[(k * NINP + 2) * H + j];
        #pragma unroll
        for (int i = 0; i < 25; i++) {
            int n = wg * 25 + i;
            o[i] += T[n][0] * w0 + T[n][1] * w1 + T[n][2] * w2;
        }
    };
    auto lhat3 = [&](const float (*S)[NINP], float (*D)[NINP], bool cheb) {
        for (int t = tid; t < NPG * NINP; t += 256) {
            int n = t / NINP, i = t % NINP;
            float v = cl * S[n][i];
            int e1 = rowstart[n + 1];
            for (int e = rowstart[n]; e < e1; e++)
                v += coefE[e] * S[colv[e]][i];
            D[n][i] = cheb ? (2.0f * v - D[n][i]) : v;
        }
        __syncthreads();
    };

    #pragma unroll
    for (int i = 0; i < 25; i++) o[i] = b1[j];
    accum3(ts[0], 0);
    __syncthreads();
    lhat3(ts[0], ts[1], false);    // Tx1
    accum3(ts[1], 1);
    __syncthreads();
    lhat3(ts[1], ts[0], true);     // Tx2 (in-place over Tx0)
    accum3(ts[0], 2);
    __syncthreads();
    lhat3(ts[0], ts[1], true);     // Tx3
    accum3(ts[1], 3);
    __syncthreads();
    lhat3(ts[1], ts[0], true);     // Tx4
    accum3(ts[0], 4);
    __syncthreads();
    #pragma unroll
    for (int i = 0; i < 25; i++)
        hb[1][wg * 25 + i][j] = fmaxf(o[i], 0.0f);
    __syncthreads();

    // ---------- layers 2 & 3 (feature width 64) ----------
    auto accum64 = [&](const float (*T)[H], const float* Wg, int k) {
        for (int fb = 0; fb < H; fb += 8) {
            float w[8];
            #pragma unroll
            for (int u = 0; u < 8; u++)
                w[u] = Wg[(k * H + fb + u) * H + j];   // L2-hot, reused 25x
            #pragma unroll
            for (int i = 0; i < 25; i++) {
                int n = wg * 25 + i;
                const float4 a  = *(const float4*)&T[n][fb];
                const float4 b4 = *(const float4*)&T[n][fb + 4];
                o[i] += a.x * w[0] + a.y * w[1] + a.z * w[2] + a.w * w[3]
                      + b4.x * w[4] + b4.y * w[5] + b4.z * w[6] + b4.w * w[7];
            }
        }
    };
    auto lhat64 = [&](const float (*S)[H], float (*D)[H], bool cheb) {
        for (int i = 0; i < 25; i++) {
            int n = wg * 25 + i;                 // wave-uniform -> no divergence
            float v = cl * S[n][j];
            int e1 = rowstart[n + 1];
            for (int e = rowstart[n]; e < e1; e++)
                v += coefE[e] * S[colv[e]][j];   // stride-1 over lanes: conflict-free
            D[n][j] = cheb ? (2.0f * v - D[n][j]) : v;
        }
        __syncthreads();
    };

    for (int layer = 0; layer < 2; layer++) {
        const float* Wg = (layer == 0) ? W2 : W3;
        const float* bg = (layer == 0) ? b2 : b3;
        #pragma unroll
        for (int i = 0; i < 25; i++) o[i] = bg[j];
        accum64(hb[1], Wg, 0);
        __syncthreads();
        lhat64(hb[1], hb[0], false);   // Tx1
        accum64(hb[0], Wg, 1);
        __syncthreads();
        lhat64(hb[0], hb[1], true);    // Tx2 (overwrites Tx0 = layer input, no longer needed)
        accum64(hb[1], Wg, 2);
        __syncthreads();
        lhat64(hb[1], hb[0], true);    // Tx3
        accum64(hb[0], Wg, 3);
        __syncthreads();
        lhat64(hb[0], hb[1], true);    // Tx4
        accum64(hb[1], Wg, 4);
        __syncthreads();
        #pragma unroll
        for (int i = 0; i < 25; i++)
            hb[1][wg * 25 + i][j] = fmaxf(o[i], 0.0f);
        __syncthreads();
    }

    // ---------- mean pool + BN + MLP + log_softmax ----------
    if (tid < H) pool[tid] = 0.0f;
    __syncthreads();
    {
        float part = 0.0f;
        #pragma unroll
        for (int i = 0; i < 25; i++) part += hb[1][wg * 25 + i][j];
        atomicAdd(&pool[j], part);
    }
    __syncthreads();
    if (tid < H) {
        float gv = pool[tid] * (1.0f / NPG);
        gv = (gv - bnm[tid]) * (1.0f / sqrtf(bnv[tid] + 1e-5f)) * bng[tid] + bnb[tid];
        gvn[tid] = gv;
    }
    __syncthreads();
    if (tid < H2) {
        float acc = fc1b[tid];
        for (int f = 0; f < H; f++) acc += gvn[f] * fc1w[f * H2 + tid];
        zf[tid] = fmaxf(acc, 0.0f);
    }
    __syncthreads();
    if (tid < NOUT) {
        float acc = fc2b[tid];
        for (int q = 0; q < H2; q++) acc += zf[q] * fc2w[q * NOUT + tid];
        logits[tid] = acc;
    }
    __syncthreads();
    if (tid == 0) {
        float m = logits[0];
        for (int t = 1; t < NOUT; t++) m = fmaxf(m, logits[t]);
        float s = 0.0f;
        for (int t = 0; t < NOUT; t++) s += expf(logits[t] - m);
        lse = m + logf(s);
    }
    __syncthreads();
    if (tid < NOUT) out[g * NOUT + tid] = logits[tid] - lse;
}

extern "C" void kernel_launch(void* const* d_in, const int* in_sizes, int n_in,
                              void* d_out, int out_size, void* d_ws, size_t ws_size,
                              hipStream_t stream) {
    const float* x    = (const float*)d_in[0];
    const int*   ei   = (const int*)d_in[1];
    // d_in[2] = batch (derivable from block id, unused)
    const float* lmax = (const float*)d_in[3];
    const float* W1   = (const float*)d_in[4];
    const float* b1   = (const float*)d_in[5];
    const float* W2   = (const float*)d_in[6];
    const float* b2   = (const float*)d_in[7];
    const float* W3   = (const float*)d_in[8];
    const float* b3   = (const float*)d_in[9];
    const float* bng  = (const float*)d_in[10];
    const float* bnb  = (const float*)d_in[11];
    const float* bnm  = (const float*)d_in[12];
    const float* bnv  = (const float*)d_in[13];
    const float* fc1w = (const float*)d_in[14];
    const float* fc1b = (const float*)d_in[15];
    const float* fc2w = (const float*)d_in[16];
    const float* fc2b = (const float*)d_in[17];

    const int E = in_sizes[1] / 2;    // 1,600,000
    const int G = in_sizes[3];        // 1,000

    cheb_fused<<<G, 256, 0, stream>>>(x, ei, lmax, W1, b1, W2, b2, W3, b3,
                                      bng, bnb, bnm, bnv, fc1w, fc1b, fc2w, fc2b,
                                      (float*)d_out, E);
}

// Round 2
// 262.058 us; speedup vs baseline: 3.1588x; 3.1588x over previous
//
#include <hip/hip_runtime.h>

#define NPG 100     // nodes per graph
#define HF 64       // hidden width
#define NPAD 112    // node dim padded to 7 x 16 tiles
#define SA 136      // row stride (bf16 elems) for Arm and Tt (128 data + 8 pad)
#define ST 72       // row stride (bf16 elems) for row-major T (64 data + 8 pad)

typedef float f4 __attribute__((ext_vector_type(4)));
typedef short bf8 __attribute__((ext_vector_type(8)));

#define SZ_ARM (NPAD * SA * 2)          // 30464
#define SZ_TRM (NPAD * ST * 2)          // 16128
#define SZ_TT  (HF * SA * 2)            // 17408
#define OFF_ARM 0
#define OFF_P   (SZ_ARM)                // Trm_P
#define OFF_PT  (OFF_P + SZ_TRM)        // Tt_P
#define OFF_Q   (OFF_PT + SZ_TT)        // Trm_Q
#define OFF_QT  (OFF_Q + SZ_TRM)        // Tt_Q
#define OFF_AF32 OFF_P                  // fp32 staging A overlays T region (setup only)
#define OFF_MISC (OFF_QT + SZ_TT)       // 97536
#define SMEM_BYTES (OFF_MISC + 2048)    // 99584

__device__ __forceinline__ unsigned short f2bf(float f) {
    unsigned u = __float_as_uint(f);
    u += 0x7fffu + ((u >> 16) & 1u);    // round-to-nearest-even
    return (unsigned short)(u >> 16);
}
__device__ __forceinline__ float bf2f(unsigned short h) {
    return __uint_as_float(((unsigned)h) << 16);
}

// One block per graph. 256 threads = 4 waves.
// Dense per-graph Laplacian in LDS; all matmuls on MFMA 16x16x32 bf16.
// L-apply computed transposed: D^T = T^T * A^T  (A-op = Tt rows, B-op = Arm rows, both b128)
// T@W computed direct:         out = Trm * W    (A-op = Trm rows b128, B-op = W from global)
__launch_bounds__(256, 1)
__global__ void cheb_mfma(const float* __restrict__ x,
                          const int*   __restrict__ ei,
                          const float* __restrict__ lambda_max,
                          const float* __restrict__ W1, const float* __restrict__ b1,
                          const float* __restrict__ W2, const float* __restrict__ b2,
                          const float* __restrict__ W3, const float* __restrict__ b3,
                          const float* __restrict__ bng, const float* __restrict__ bnb,
                          const float* __restrict__ bnm, const float* __restrict__ bnv,
                          const float* __restrict__ fc1w, const float* __restrict__ fc1b,
                          const float* __restrict__ fc2w, const float* __restrict__ fc2b,
                          float* __restrict__ out, int E_total, int epg)
{
    extern __shared__ char sm[];

    const int tid = threadIdx.x;
    const int g = blockIdx.x;
    const int ebase = g * epg;
    const int nbase = g * NPG;
    const int wg = tid >> 6;    // wave 0..3
    const int lane = tid & 63;
    const int q = lane >> 4;    // quad 0..3
    const int t = lane & 15;

    float* Af     = (float*)(sm + OFF_AF32);
    int*   deg    = (int*)(sm + OFF_MISC);            // 400 B
    float* dis    = (float*)(sm + OFF_MISC + 448);    // 400 B
    float* pool   = (float*)(sm + OFF_MISC + 896);    // 256 B
    float* gvn    = (float*)(sm + OFF_MISC + 1152);   // 256 B
    float* zf     = (float*)(sm + OFF_MISC + 1408);   // 128 B
    float* logits = (float*)(sm + OFF_MISC + 1536);   // 64 B
    float* lsep   = (float*)(sm + OFF_MISC + 1600);

    const float lam = lambda_max[g];
    const float two_l = 2.0f / lam;
    const float cl = two_l - 1.0f;   // diagonal of Lhat

    // ---------------- build dense A (fp32 staging, then bf16) ----------------
    for (int i = tid; i < 2500; i += 256) ((f4*)Af)[i] = (f4){0.f, 0.f, 0.f, 0.f};
    if (tid < NPG) deg[tid] = 0;
    __syncthreads();
    for (int e = tid; e < epg; e += 256)
        atomicAdd(&deg[ei[ebase + e] - nbase], 1);
    __syncthreads();
    if (tid < NPG) {
        int d = deg[tid];
        dis[tid] = d > 0 ? rsqrtf((float)d) : 0.0f;
    }
    __syncthreads();
    for (int e = tid; e < epg; e += 256) {
        int r = ei[ebase + e] - nbase;
        int c = ei[E_total + ebase + e] - nbase;
        atomicAdd(&Af[r * NPG + c], -two_l * dis[r] * dis[c]);   // duplicates accumulate
    }
    __syncthreads();
    if (tid < NPG) Af[tid * NPG + tid] += cl;
    __syncthreads();
    // convert to Arm bf16 [112][136], data cols 0..127 (zero-padded outside 100x100)
    for (int u = tid; u < NPAD * 64; u += 256) {
        int n = u >> 6;
        int kp = (u & 63) * 2;
        float v0 = (n < NPG && kp < NPG) ? Af[n * NPG + kp] : 0.f;
        float v1 = (n < NPG && kp + 1 < NPG) ? Af[n * NPG + kp + 1] : 0.f;
        unsigned pk = (unsigned)f2bf(v0) | ((unsigned)f2bf(v1) << 16);
        *(unsigned*)(sm + OFF_ARM + (n * SA + kp) * 2) = pk;
    }
    __syncthreads();   // conversion reads of Af done before T buffers overwrite it

    // ---------------- init T buffers: zero all, then x into P ----------------
    for (int i = tid; i < (2 * (SZ_TRM + SZ_TT)) / 16; i += 256)
        ((f4*)(sm + OFF_P))[i] = (f4){0.f, 0.f, 0.f, 0.f};
    __syncthreads();
    if (tid < NPG) {
        float x0 = x[(nbase + tid) * 3 + 0];
        float x1 = x[(nbase + tid) * 3 + 1];
        float x2 = x[(nbase + tid) * 3 + 2];
        unsigned short h0 = f2bf(x0), h1 = f2bf(x1), h2 = f2bf(x2);
        *(unsigned*)(sm + OFF_P + (tid * ST) * 2) = (unsigned)h0 | ((unsigned)h1 << 16);
        *(unsigned short*)(sm + OFF_P + (tid * ST + 2) * 2) = h2;
        *(unsigned short*)(sm + OFF_PT + (0 * SA + tid) * 2) = h0;
        *(unsigned short*)(sm + OFF_PT + (1 * SA + tid) * 2) = h1;
        *(unsigned short*)(sm + OFF_PT + (2 * SA + tid) * 2) = h2;
    }
    __syncthreads();

    // ---------------- 3 ChebConv layers ----------------
    f4 acc[7];
    const float* Ws[3] = {W1, W2, W3};
    const float* bs[3] = {b1, b2, b3};
    const int offR[2] = {OFF_P, OFF_Q};
    const int offT[2] = {OFF_PT, OFF_QT};

    for (int L = 0; L < 3; L++) {
        const bool l1 = (L == 0);
        const float* Wp = Ws[L];
        #pragma unroll
        for (int m = 0; m < 7; m++) acc[m] = (f4){0.f, 0.f, 0.f, 0.f};

        // out += T @ W[k5]; wave wg owns output cols 16wg..16wg+15
        auto TW = [&](int offTrm, int k5) {
            const int fo = 16 * wg + t;
            bf8 bf0 = {}, bf1 = {};
            #pragma unroll
            for (int j = 0; j < 8; j++) {
                int fi = q * 8 + j;
                float v;
                if (l1) v = (fi < 3) ? Wp[(k5 * 3 + fi) * HF + fo] : 0.f;
                else    v = Wp[(k5 * HF + fi) * HF + fo];
                bf0[j] = (short)f2bf(v);
            }
            if (!l1) {
                #pragma unroll
                for (int j = 0; j < 8; j++) {
                    int fi = 32 + q * 8 + j;
                    bf1[j] = (short)f2bf(Wp[(k5 * HF + fi) * HF + fo]);
                }
            }
            #pragma unroll
            for (int Mt = 0; Mt < 7; Mt++) {
                const char* base = sm + offTrm + ((Mt * 16 + t) * ST) * 2;
                bf8 a0 = *(const bf8*)(base + (q * 8) * 2);
                acc[Mt] = __builtin_amdgcn_mfma_f32_16x16x32_bf16(a0, bf0, acc[Mt], 0, 0, 0);
                if (!l1) {
                    bf8 a1 = *(const bf8*)(base + (32 + q * 8) * 2);
                    acc[Mt] = __builtin_amdgcn_mfma_f32_16x16x32_bf16(a1, bf1, acc[Mt], 0, 0, 0);
                }
            }
        };

        // dst = Lhat*src (first) or 2*Lhat*src - dst_old (cheb); wave wg owns feat rows 16wg..+15
        auto LHAT = [&](int src, int dst, bool cheb) {
            bf8 af[4];
            #pragma unroll
            for (int Ks = 0; Ks < 4; Ks++)
                af[Ks] = *(const bf8*)(sm + offT[src] + ((16 * wg + t) * SA + Ks * 32 + q * 8) * 2);
            #pragma unroll
            for (int Nt = 0; Nt < 7; Nt++) {
                f4 c = (f4){0.f, 0.f, 0.f, 0.f};
                const char* brow = sm + OFF_ARM + ((Nt * 16 + t) * SA) * 2;
                #pragma unroll
                for (int Ks = 0; Ks < 4; Ks++) {
                    bf8 b = *(const bf8*)(brow + (Ks * 32 + q * 8) * 2);
                    c = __builtin_amdgcn_mfma_f32_16x16x32_bf16(af[Ks], b, c, 0, 0, 0);
                }
                const int node = Nt * 16 + t;
                char* prm = sm + offR[dst] + (node * ST + 16 * wg + 4 * q) * 2;
                float v0, v1, v2, v3;
                if (cheb) {
                    uint2 old = *(const uint2*)prm;
                    v0 = 2.f * c[0] - bf2f((unsigned short)(old.x & 0xffff));
                    v1 = 2.f * c[1] - bf2f((unsigned short)(old.x >> 16));
                    v2 = 2.f * c[2] - bf2f((unsigned short)(old.y & 0xffff));
                    v3 = 2.f * c[3] - bf2f((unsigned short)(old.y >> 16));
                } else { v0 = c[0]; v1 = c[1]; v2 = c[2]; v3 = c[3]; }
                unsigned short h0 = f2bf(v0), h1 = f2bf(v1), h2 = f2bf(v2), h3 = f2bf(v3);
                uint2 pk;
                pk.x = (unsigned)h0 | ((unsigned)h1 << 16);
                pk.y = (unsigned)h2 | ((unsigned)h3 << 16);
                *(uint2*)prm = pk;
                const int fb = 16 * wg + 4 * q;
                *(unsigned short*)(sm + offT[dst] + ((fb + 0) * SA + node) * 2) = h0;
                *(unsigned short*)(sm + offT[dst] + ((fb + 1) * SA + node) * 2) = h1;
                *(unsigned short*)(sm + offT[dst] + ((fb + 2) * SA + node) * 2) = h2;
                *(unsigned short*)(sm + offT[dst] + ((fb + 3) * SA + node) * 2) = h3;
            }
        };

        TW(offR[0], 0);                    // Tx0 contribution
        int src = 0, dst = 1;
        for (int s = 1; s <= 4; s++) {
            LHAT(src, dst, s >= 2);        // Tx_s
            __syncthreads();
            TW(offR[dst], s);
            int tmp = src; src = dst; dst = tmp;
        }
        __syncthreads();                   // WAR: all TW readers done before h overwrite

        const float bias = bs[L][16 * wg + t];
        if (L < 2) {
            // h = relu(acc + b) -> P (both orientations)
            const int fo = 16 * wg + t;
            #pragma unroll
            for (int Mt = 0; Mt < 7; Mt++) {
                unsigned short h[4];
                #pragma unroll
                for (int r = 0; r < 4; r++)
                    h[r] = f2bf(fmaxf(acc[Mt][r] + bias, 0.f));
                const int nb = Mt * 16 + 4 * q;
                #pragma unroll
                for (int r = 0; r < 4; r++)
                    *(unsigned short*)(sm + OFF_P + ((nb + r) * ST + fo) * 2) = h[r];
                uint2 pk;
                pk.x = (unsigned)h[0] | ((unsigned)h[1] << 16);
                pk.y = (unsigned)h[2] | ((unsigned)h[3] << 16);
                *(uint2*)(sm + OFF_PT + (fo * SA + nb) * 2) = pk;
            }
            __syncthreads();
        } else {
            // mean-pool directly from C regs (nodes < 100 only)
            float ssum = 0.f;
            #pragma unroll
            for (int Mt = 0; Mt < 7; Mt++) {
                #pragma unroll
                for (int r = 0; r < 4; r++) {
                    int node = Mt * 16 + 4 * q + r;
                    float h = fmaxf(acc[Mt][r] + bias, 0.f);
                    if (node < NPG) ssum += h;
                }
            }
            ssum += __shfl_xor(ssum, 16, 64);
            ssum += __shfl_xor(ssum, 32, 64);
            if (q == 0) pool[16 * wg + t] = ssum;
            __syncthreads();
        }
    }

    // ---------------- BN + MLP + log_softmax ----------------
    if (tid < HF) {
        float gv = pool[tid] * (1.0f / NPG);
        gv = (gv - bnm[tid]) * rsqrtf(bnv[tid] + 1e-5f) * bng[tid] + bnb[tid];
        gvn[tid] = gv;
    }
    __syncthreads();
    if (tid < 32) {
        float a = fc1b[tid];
        for (int f = 0; f < HF; f++) a += gvn[f] * fc1w[f * 32 + tid];
        zf[tid] = fmaxf(a, 0.f);
    }
    __syncthreads();
    if (tid < 10) {
        float a = fc2b[tid];
        for (int k = 0; k < 32; k++) a += zf[k] * fc2w[k * 10 + tid];
        logits[tid] = a;
    }
    __syncthreads();
    if (tid == 0) {
        float m = logits[0];
        for (int i = 1; i < 10; i++) m = fmaxf(m, logits[i]);
        float s = 0.f;
        for (int i = 0; i < 10; i++) s += expf(logits[i] - m);
        lsep[0] = m + logf(s);
    }
    __syncthreads();
    if (tid < 10) out[g * 10 + tid] = logits[tid] - lsep[0];
}

extern "C" void kernel_launch(void* const* d_in, const int* in_sizes, int n_in,
                              void* d_out, int out_size, void* d_ws, size_t ws_size,
                              hipStream_t stream) {
    const float* x    = (const float*)d_in[0];
    const int*   ei   = (const int*)d_in[1];
    const float* lmax = (const float*)d_in[3];
    const float* W1   = (const float*)d_in[4];
    const float* b1   = (const float*)d_in[5];
    const float* W2   = (const float*)d_in[6];
    const float* b2   = (const float*)d_in[7];
    const float* W3   = (const float*)d_in[8];
    const float* b3   = (const float*)d_in[9];
    const float* bng  = (const float*)d_in[10];
    const float* bnb  = (const float*)d_in[11];
    const float* bnm  = (const float*)d_in[12];
    const float* bnv  = (const float*)d_in[13];
    const float* fc1w = (const float*)d_in[14];
    const float* fc1b = (const float*)d_in[15];
    const float* fc2w = (const float*)d_in[16];
    const float* fc2b = (const float*)d_in[17];

    const int E = in_sizes[1] / 2;     // 1,600,000
    const int G = in_sizes[3];         // 1,000
    const int epg = E / G;             // 1,600

    hipFuncSetAttribute((const void*)cheb_mfma,
                        hipFuncAttributeMaxDynamicSharedMemorySize, SMEM_BYTES);

    cheb_mfma<<<G, 256, SMEM_BYTES, stream>>>(x, ei, lmax, W1, b1, W2, b2, W3, b3,
                                              bng, bnb, bnm, bnv, fc1w, fc1b, fc2w, fc2b,
                                              (float*)d_out, E, epg);
}